// Round 8
// baseline (6674.026 us; speedup 1.0000x reference)
//
#include <hip/hip_runtime.h>

// RnnTagger (f32 in / f32 out): tokens[64*512] i32; emb[50000,256]; W_ih[1536,256];
// W_hh[1536,512]; b_ih[1536]; b_hh[1536]; W_tag[64,512]; b_tag[64].
// d_out f32: tag_logits [64,512,64] then preds [64,512] flat.
//
// f32-faithful MFMA via f16 double-split: x ~= hi + lo/4096 (hi,lo f16); product
// = 3 f16 MFMAs (m += Ah*Wh; s += Al*Wh + Ah*Wl; result = m + s/4096).
//
// R14 = third submission of the R12 experiment (R12/R13 both died on
// "container failed twice" with no kernel-level evidence; source audited:
// in-bounds, aligned, deadlock-free, launchable at 224 VGPR). If this fails
// on infra again, next round reverts to the R11 base.
// R12 = R11 + forced W_hh hi-plane register residency. R11 post-mortem: traffic
// cut confirmed (FETCH 668->404 MB) but only -1.5us/step -> bytes no longer
// dominant; largest reducible term is the W_hh L2 stream on the F-phase
// critical path (393 KB/WG/step ~ 2.6us at ~150GB/s per-CU L2 BW, serialized
// after h arrives). R9's register-residency attempt was nullified by compiler
// rematerialization (VGPR stayed 128). The launder asm volatile("" : "+v")
// makes each preloaded u32x4 an asm output -> opaque provenance -> no remat:
// 96 VGPRs/lane, 128+96=224 < 256 budget at 2 waves/SIMD.
// Phase F stream halves to 196 KB/step (lo plane only).
// Everything else identical to R11 (512-thr WGs, wave-pair K-split, 4B pk
// flag-only exchange, u64 atomic payload reads, de-packed LDS h planes,
// per-producer flags in d_out's preds region).
//
// ws (72,482,816 B):
//   [0,+262144)         h pk dbuf  u32[2][64][512]
//   [524288,+3145728)   whh2  [hi/lo][1536][512] f16
//   [3670016,+1572864)  wih2  [hi/lo][1536][256] f16
//   [5242880,+131072)   wtag2 [hi/lo][64][512] f16
//   [5373952,+67108864) st    [b*512+t][512] f32

typedef unsigned short ushortT;
typedef unsigned long long u64c;
typedef float f32x4 __attribute__((ext_vector_type(4)));
typedef _Float16 f16x8 __attribute__((ext_vector_type(8)));
typedef unsigned int u32x4 __attribute__((ext_vector_type(4)));

#define MFMAH(a, b, c) __builtin_amdgcn_mfma_f32_16x16x32_f16((a), (b), (c), 0, 0, 0)
#define KSC (1.0f / 4096.0f)

__device__ __forceinline__ void splitf(float x, ushortT& hi, ushortT& lo) {
    _Float16 h = (_Float16)x;
    float r = x - (float)h;
    _Float16 l = (_Float16)(r * 4096.0f);
    hi = __builtin_bit_cast(ushortT, h);
    lo = __builtin_bit_cast(ushortT, l);
}

// ---------- k0: split weights into f16 hi/lo planes ----------
__global__ __launch_bounds__(256) void split_weights(
    const float* __restrict__ Whh, const float* __restrict__ Wih,
    const float* __restrict__ Wtag, ushortT* __restrict__ wh2,
    ushortT* __restrict__ wi2, ushortT* __restrict__ wt2)
{
    const int i = blockIdx.x * 256 + threadIdx.x;
    ushortT hi, lo;
    if (i < 786432) {                       // 1536*512
        splitf(Whh[i], hi, lo);
        wh2[i] = hi; wh2[786432 + i] = lo;
    } else if (i < 786432 + 393216) {       // 1536*256
        const int j = i - 786432;
        splitf(Wih[j], hi, lo);
        wi2[j] = hi; wi2[393216 + j] = lo;
    } else if (i < 786432 + 393216 + 32768) {   // 64*512
        const int j = i - 786432 - 393216;
        splitf(Wtag[j], hi, lo);
        wt2[j] = hi; wt2[32768 + j] = lo;
    }
}

// ---------- k1: zero h pk double buffer + flags ----------
__global__ void init_ws(uint4* p, uint4* f) {
    int i = blockIdx.x * blockDim.x + threadIdx.x;
    uint4 z; z.x = 0u; z.y = 0u; z.z = 0u; z.w = 0u;
    if (i < 16384) p[i] = z;    // 262144 B / 16
    if (i < 256)   f[i] = z;    // 4096 B of flags
}

// ---------- k2: fused gi + serial GRU recurrence ----------
// 32 WGs x 512 (8 waves = 2 waves/SIMD). cluster = bid>>3 owns batch rows
// [cluster*16,+16); jg = bid&7 owns h-cols [jg*64,+64). Wave pair (w, w+4)
// owns cols jg*64 + w*16 + [0,16), K-split across the pair.
__global__ __launch_bounds__(512, 1) void gru_rec(
    const int* __restrict__ tok, const float* __restrict__ emb,
    const ushortT* __restrict__ wih2, const ushortT* __restrict__ whh2,
    const float* __restrict__ bih, const float* __restrict__ bhh,
    unsigned* __restrict__ hb32, float* __restrict__ st,
    unsigned* __restrict__ flags)
{
    __shared__ ushortT xl[2][2][16][264];   // 33792 B: x dbuf [buf][hi/lo][16 b][256k pad]
    __shared__ ushortT hlh[16 * 520];       // 16640 B: h hi plane [16 rows][512 + pad 8]
    __shared__ ushortT hll[16 * 520];       // 16640 B: h lo plane
    __shared__ f32x4 pl[4][8][64];          // 32768 B: upper-wave partials [u][vec][lane]

    const int bid = blockIdx.x;
    const int cluster = bid >> 3;
    const int jg = bid & 7;
    const int tid = threadIdx.x;
    const int wave = tid >> 6;
    const int lane = tid & 63;
    const int wl = wave & 3;                // pair column-slot 0..3
    const bool upper = wave >= 4;
    const int ln = lane & 15, quad = lane >> 4;
    const int m0 = cluster * 16;
    const int j_lane = jg * 64 + wl * 16 + ln;

    // 128B-padded flags: flags[(cluster*8 + jg)*32]; threads 0..7 poll.
    unsigned* ownp = flags + (unsigned)(cluster * 8 + jg) * 32u;

    const float c_r  = bih[j_lane]        + bhh[j_lane];
    const float c_z  = bih[512 + j_lane]  + bhh[512 + j_lane];
    const float bi_n = bih[1024 + j_lane];
    const float bh_n = bhh[1024 + j_lane];

    const int fks0 = upper ? 8 : 0;
    const int cks0 = upper ? 4 : 0;

    // W_hh HI plane register-resident: 24 x u32x4 = 96 VGPRs/lane. The empty
    // asm with "+v" makes each value an asm output -> opaque provenance ->
    // the compiler cannot rematerialize the loads inside the t-loop (R9's
    // failure mode: VGPR_Count stayed 128, stream unchanged).
    u32x4 whhHiR[24];
#pragma unroll
    for (int ksi = 0; ksi < 8; ++ksi) {
        const int k = (fks0 + ksi) * 32 + quad * 8;
#pragma unroll
        for (int g = 0; g < 3; ++g)
            whhHiR[ksi * 3 + g] = *reinterpret_cast<const u32x4*>(
                whh2 + (size_t)(g * 512 + j_lane) * 512 + k);
    }
#pragma unroll
    for (int i = 0; i < 24; ++i)
        asm volatile("" : "+v"(whhHiR[i]));
    const ushortT* wlo = whh2 + 786432;     // W_hh lo plane (streamed from L2)

    // Prologue: upper 256 threads stage x_0 into LDS buf 0.
    const int xr = (tid & 255) >> 4, xc = (tid & 15) * 16;
    if (upper) {
        const int token = tok[(m0 + xr) * 512];
        const float* xsrc = emb + (size_t)token * 256 + xc;
#pragma unroll
        for (int i = 0; i < 16; ++i) {
            ushortT hi, lo; splitf(xsrc[i], hi, lo);
            xl[0][0][xr][xc + i] = hi; xl[0][1][xr][xc + i] = lo;
        }
    }
    __syncthreads();

    float hprev[4] = {0.f, 0.f, 0.f, 0.f};

    for (int t = 0; t < 512; ++t) {
        const int rb = t & 1;
        const int wb = rb ^ 1;
        const u64c* tile64 =
            (const u64c*)(hb32 + (size_t)rb * 32768 + (size_t)m0 * 512);

        // (B) upper: x_{t+1} global loads into regs (published in phase H)
        f32x4 xv[4];
        if (upper) {
            const int tp = (t + 1) & 511;
            const int xtoken = tok[(m0 + xr) * 512 + tp];
            const float* xsrc = emb + (size_t)xtoken * 256 + xc;
#pragma unroll
            for (int i = 0; i < 4; ++i)
                xv[i] = *reinterpret_cast<const f32x4*>(xsrc + i * 4);
        }

        // per-pair partial accumulators
        f32x4 m_r = (f32x4){0.f,0.f,0.f,0.f}, s_r = (f32x4){0.f,0.f,0.f,0.f};
        f32x4 m_z = (f32x4){0.f,0.f,0.f,0.f}, s_z = (f32x4){0.f,0.f,0.f,0.f};
        f32x4 m_gin = (f32x4){0.f,0.f,0.f,0.f}, s_gin = (f32x4){0.f,0.f,0.f,0.f};
        f32x4 m_ghn = (f32x4){0.f,0.f,0.f,0.f}, s_ghn = (f32x4){0.f,0.f,0.f,0.f};

        // (C) gi = x_t @ W_ih^T, K-split: lower ks 0..3, upper ks 4..7
#pragma unroll
        for (int ksi = 0; ksi < 4; ++ksi) {
            const int k = (cks0 + ksi) * 32 + quad * 8;
            f16x8 Axh = *reinterpret_cast<const f16x8*>(&xl[rb][0][ln][k]);
            f16x8 Axl = *reinterpret_cast<const f16x8*>(&xl[rb][1][ln][k]);
#pragma unroll
            for (int g = 0; g < 3; ++g) {
                const ushortT* wr = wih2 + (size_t)(g * 512 + j_lane) * 256 + k;
                f16x8 Wh = *reinterpret_cast<const f16x8*>(wr);
                f16x8 Wl = *reinterpret_cast<const f16x8*>(wr + 393216);
                if (g == 0) {
                    m_r = MFMAH(Axh, Wh, m_r);
                    s_r = MFMAH(Axl, Wh, s_r);
                    s_r = MFMAH(Axh, Wl, s_r);
                } else if (g == 1) {
                    m_z = MFMAH(Axh, Wh, m_z);
                    s_z = MFMAH(Axl, Wh, s_z);
                    s_z = MFMAH(Axh, Wl, s_z);
                } else {
                    m_gin = MFMAH(Axh, Wh, m_gin);
                    s_gin = MFMAH(Axl, Wh, s_gin);
                    s_gin = MFMAH(Axh, Wl, s_gin);
                }
            }
        }

        // (D0) flag wait: threads 0..7 each spin on one producer flag
        if (tid < 8) {
            const unsigned want = (unsigned)t;
            unsigned* pp = flags + (unsigned)(cluster * 8 + tid) * 32u;
            unsigned f = __hip_atomic_load(pp, __ATOMIC_RELAXED,
                                           __HIP_MEMORY_SCOPE_AGENT);
            while (f < want) {
                __builtin_amdgcn_s_sleep(2);
                f = __hip_atomic_load(pp, __ATOMIC_RELAXED,
                                      __HIP_MEMORY_SCOPE_AGENT);
            }
        }
        __syncthreads();   // all 8 producer flags confirmed across the WG

        // (A) payload read: 8 u64 agent-coherent atomic loads per thread,
        // each carrying TWO 4B pk's. Flag-sync guarantees visibility.
        u64c v[8];
#pragma unroll
        for (int j = 0; j < 8; ++j)
            v[j] = __hip_atomic_load(tile64 + tid + 512 * j,
                                     __ATOMIC_RELAXED, __HIP_MEMORY_SCOPE_AGENT);

        // (E) publish DE-PACKED hi/lo planes to LDS: 2 cols per atom,
        // packed u32 writes (4B-aligned since c2 and row stride are even)
#pragma unroll
        for (int j = 0; j < 8; ++j) {
            const int a = tid + 512 * j;        // u64 index in [0,4096)
            const int row = a >> 8;             // 0..15
            const int c2 = (a & 255) * 2;       // 0,2,...,510
            const unsigned lo32 = (unsigned)v[j];
            const unsigned hi32 = (unsigned)(v[j] >> 32);
            *reinterpret_cast<unsigned*>(&hlh[row * 520 + c2]) =
                (lo32 & 0xffffu) | (hi32 << 16);
            *reinterpret_cast<unsigned*>(&hll[row * 520 + c2]) =
                (lo32 >> 16) | (hi32 & 0xffff0000u);
        }
        __syncthreads();

        // (F) gh = h_{t-1} @ W_hh^T, K-split: lower ks 0..7, upper ks 8..15.
        // A-frags: direct b128 from de-packed planes. Wh: REGISTERS. Wl: L2.
#pragma unroll
        for (int ksi = 0; ksi < 8; ++ksi) {
            const int k = (fks0 + ksi) * 32 + quad * 8;
            f16x8 Ah = *reinterpret_cast<const f16x8*>(&hlh[ln * 520 + k]);
            f16x8 Al = *reinterpret_cast<const f16x8*>(&hll[ln * 520 + k]);
#pragma unroll
            for (int g = 0; g < 3; ++g) {
                f16x8 Wh = __builtin_bit_cast(f16x8, whhHiR[ksi * 3 + g]);
                f16x8 Wl = *reinterpret_cast<const f16x8*>(
                    wlo + (size_t)(g * 512 + j_lane) * 512 + k);
                if (g == 0) {
                    m_r = MFMAH(Ah, Wh, m_r);
                    s_r = MFMAH(Al, Wh, s_r);
                    s_r = MFMAH(Ah, Wl, s_r);
                } else if (g == 1) {
                    m_z = MFMAH(Ah, Wh, m_z);
                    s_z = MFMAH(Al, Wh, s_z);
                    s_z = MFMAH(Ah, Wl, s_z);
                } else {
                    m_ghn = MFMAH(Ah, Wh, m_ghn);
                    s_ghn = MFMAH(Al, Wh, s_ghn);
                    s_ghn = MFMAH(Ah, Wl, s_ghn);
                }
            }
        }

        // (R) upper waves dump partials to LDS (lane-consecutive 16B: conflict-free)
        if (upper) {
            const int u = wave - 4;
            pl[u][0][lane] = m_r;   pl[u][1][lane] = s_r;
            pl[u][2][lane] = m_z;   pl[u][3][lane] = s_z;
            pl[u][4][lane] = m_gin; pl[u][5][lane] = s_gin;
            pl[u][6][lane] = m_ghn; pl[u][7][lane] = s_ghn;
        }
        __syncthreads();

        float hn4[4];
        if (!upper) {
            // combine K-halves
            m_r   += pl[wave][0][lane]; s_r   += pl[wave][1][lane];
            m_z   += pl[wave][2][lane]; s_z   += pl[wave][3][lane];
            m_gin += pl[wave][4][lane]; s_gin += pl[wave][5][lane];
            m_ghn += pl[wave][6][lane]; s_ghn += pl[wave][7][lane];

            // (G) gates + h_new; 4B pk stores (drained by the next barrier)
            unsigned* hw32 = hb32 + (size_t)wb * 32768;
#pragma unroll
            for (int r4 = 0; r4 < 4; ++r4) {
                const float pre_r = m_r[r4] + s_r[r4] * KSC + c_r;
                const float pre_z = m_z[r4] + s_z[r4] * KSC + c_z;
                const float gin   = m_gin[r4] + s_gin[r4] * KSC + bi_n;
                const float ghn   = m_ghn[r4] + s_ghn[r4] * KSC + bh_n;
                const float rr = 1.f / (1.f + expf(-pre_r));
                const float zz = 1.f / (1.f + expf(-pre_z));
                const float nn = tanhf(gin + rr * ghn);
                const float hn = (1.f - zz) * nn + zz * hprev[r4];
                hprev[r4] = hn;
                hn4[r4] = hn;
                ushortT hi, lo; splitf(hn, hi, lo);
                const unsigned pk = (unsigned)hi | ((unsigned)lo << 16);
                const int b = m0 + quad * 4 + r4;
                __hip_atomic_store(&hw32[b * 512 + j_lane], pk,
                                   __ATOMIC_RELAXED, __HIP_MEMORY_SCOPE_AGENT);
            }
        } else {
            // (H) publish x_{t+1} into LDS buffer wb
#pragma unroll
            for (int i = 0; i < 16; ++i) {
                ushortT hi, lo; splitf(xv[i >> 2][i & 3], hi, lo);
                xl[wb][0][xr][xc + i] = hi; xl[wb][1][xr][xc + i] = lo;
            }
        }

        // barrier: each wave drains its own vmcnt before arriving -> all lower
        // waves' payload stores are at the coherence point; also xl/hl turnover
        __syncthreads();
        if (tid == 0)
            __hip_atomic_store(ownp, (unsigned)(t + 1),
                               __ATOMIC_RELAXED, __HIP_MEMORY_SCOPE_AGENT);

        // st stores — consumed only by k3 after this kernel; off critical path
        if (!upper) {
#pragma unroll
            for (int r4 = 0; r4 < 4; ++r4) {
                const int b = m0 + quad * 4 + r4;
                st[((size_t)b * 512 + t) * 512 + j_lane] = hn4[r4];
            }
        }
    }
}

// ---------- k3: tag logits + argmax + PAD mask (R5-identical) ----------
__global__ __launch_bounds__(256) void tag_argmax(
    const float* __restrict__ st, const ushortT* __restrict__ wtag2,
    const float* __restrict__ btag, const int* __restrict__ tok,
    float* __restrict__ out)
{
    const int wave = threadIdx.x >> 6;
    const int lane = threadIdx.x & 63;
    const int ln = lane & 15, quad = lane >> 4;
    const int mt = blockIdx.x * 4 + wave;   // 0..2047

    const float* arow = st + (size_t)(mt * 16 + ln) * 512;
    f32x4 am[4], as_[4];
#pragma unroll
    for (int ti = 0; ti < 4; ++ti) { am[ti] = (f32x4){0.f,0.f,0.f,0.f}; as_[ti] = (f32x4){0.f,0.f,0.f,0.f}; }

#pragma unroll
    for (int ks = 0; ks < 16; ++ks) {
        const int k = ks * 32 + quad * 8;
        f16x8 Ah, Al;
#pragma unroll
        for (int e = 0; e < 8; ++e) {
            const float x = arow[k + e];
            _Float16 h = (_Float16)x;
            Ah[e] = h;
            Al[e] = (_Float16)((x - (float)h) * 4096.0f);
        }
#pragma unroll
        for (int ti = 0; ti < 4; ++ti) {
            const ushortT* wr = wtag2 + (size_t)(ti * 16 + ln) * 512 + k;
            f16x8 Wh = *reinterpret_cast<const f16x8*>(wr);
            f16x8 Wl = *reinterpret_cast<const f16x8*>(wr + 32768);
            am[ti]  = MFMAH(Ah, Wh, am[ti]);
            as_[ti] = MFMAH(Ah, Wl, as_[ti]);
            as_[ti] = MFMAH(Al, Wh, as_[ti]);
        }
    }

    float vals[4][4];
#pragma unroll
    for (int ti = 0; ti < 4; ++ti) {
        const float bb = btag[ti * 16 + ln];
#pragma unroll
        for (int r = 0; r < 4; ++r) vals[ti][r] = am[ti][r] + as_[ti][r] * KSC + bb;
    }
#pragma unroll
    for (int ti = 0; ti < 4; ++ti)
#pragma unroll
        for (int r = 0; r < 4; ++r) {
            const int row = mt * 16 + quad * 4 + r;
            out[(size_t)row * 64 + ti * 16 + ln] = vals[ti][r];
        }
#pragma unroll
    for (int r = 0; r < 4; ++r) {
        float best = vals[0][r];
        int bc = ln;
#pragma unroll
        for (int ti = 1; ti < 4; ++ti) {
            const float v = vals[ti][r];
            const int c = ti * 16 + ln;
            if (v > best) { best = v; bc = c; }
        }
        for (int off = 1; off < 16; off <<= 1) {
            const float ov = __shfl_xor(best, off);
            const int oc = __shfl_xor(bc, off);
            if (ov > best || (ov == best && oc < bc)) { best = ov; bc = oc; }
        }
        if (ln == 0) {
            const int row = mt * 16 + quad * 4 + r;   // = b*512+t = token idx
            const int token = tok[row];
            const int pred = (token != 0) ? bc : 0;
            out[2097152 + (size_t)row] = (float)pred;
        }
    }
}

extern "C" void kernel_launch(void* const* d_in, const int* in_sizes, int n_in,
                              void* d_out, int out_size, void* d_ws, size_t ws_size,
                              hipStream_t stream) {
    const int*   tokens = (const int*)d_in[0];
    const float* emb    = (const float*)d_in[1];
    const float* Wih    = (const float*)d_in[2];
    const float* Whh    = (const float*)d_in[3];
    const float* bih    = (const float*)d_in[4];
    const float* bhh    = (const float*)d_in[5];
    const float* Wtag   = (const float*)d_in[6];
    const float* btag   = (const float*)d_in[7];

    char* ws = (char*)d_ws;
    unsigned* hb32  = (unsigned*)ws;                 // 262,144 B used
    ushortT*  whh2  = (ushortT*)(ws + 524288);       // 3,145,728 B
    ushortT*  wih2  = (ushortT*)(ws + 3670016);      // 1,572,864 B
    ushortT*  wtag2 = (ushortT*)(ws + 5242880);      // 131,072 B
    float*    stf   = (float*)(ws + 5373952);        // 67,108,864 B (total 72.48 MB)
    float*    out   = (float*)d_out;

    // Sync flags live in d_out's preds region (scratch during gru_rec;
    // tag_argmax rewrites every preds element afterwards). 32 flags, 128B pad.
    unsigned* flags = (unsigned*)(out + 2097152);

    split_weights<<<4736, 256, 0, stream>>>(Whh, Wih, Wtag, whh2, wih2, wtag2);
    init_ws<<<128, 256, 0, stream>>>((uint4*)ws, (uint4*)flags);
    gru_rec<<<32, 512, 0, stream>>>(tokens, emb, wih2, whh2, bih, bhh, hb32, stf, flags);
    tag_argmax<<<512, 256, 0, stream>>>(stf, wtag2, btag, tokens, out);
}